// Round 1
// 335.454 us; speedup vs baseline: 1.0228x; 1.0228x over previous
//
#include <hip/hip_runtime.h>

typedef unsigned short u16;
typedef __attribute__((ext_vector_type(8))) short short8;
typedef __attribute__((ext_vector_type(4))) float f32x4;
typedef __attribute__((ext_vector_type(16))) float f32x16;
typedef __attribute__((ext_vector_type(4))) unsigned u32x4;

struct __align__(8) us4 { u16 x, y, z, w; };
struct __align__(8) ui2 { unsigned x, y; };

// log2(e) / (sqrt(64) + 1e-6)  -- folded into W_q at prep time
#define CEXP (1.44269504089f / (8.0f + 1e-6f))

// ---------- helpers ----------
__device__ __forceinline__ u16 f2bf(float f) {
  unsigned u = __builtin_bit_cast(unsigned, f);
  unsigned r = (u + 0x7FFFu + ((u >> 16) & 1u)) >> 16;  // RNE
  return (u16)r;
}

// truncation pack: {bf16(b)[hi16] , bf16(a)[lo16]} in ONE v_perm_b32
__device__ __forceinline__ unsigned pack_bf2_trunc(float a, float b) {
  return __builtin_amdgcn_perm(__builtin_bit_cast(unsigned, b),
                               __builtin_bit_cast(unsigned, a), 0x07060302u);
}

__device__ __forceinline__ void async_load16(const void* g, void* l) {
  __builtin_amdgcn_global_load_lds((const __attribute__((address_space(1))) void*)g,
                                   (__attribute__((address_space(3))) void*)l, 16, 0, 0);
}

// ---------- weight prep ----------
// wqkvT: [1536,512] bf16 (rows 0-511 = Wq^T*CEXP, 512-1023 = Wk^T, 1024-1535 = Wv^T)
__global__ void prep_weights(const float* __restrict__ Wq, const float* __restrict__ Wk,
                             const float* __restrict__ Wv, const float* __restrict__ Wo,
                             const float* __restrict__ w1, const float* __restrict__ w2,
                             u16* __restrict__ wqkvT, u16* __restrict__ woT,
                             u16* __restrict__ w1b, u16* __restrict__ w2b) {
  const int z = blockIdx.y;
  const int stride = gridDim.x * blockDim.x;
  const int i0 = blockIdx.x * blockDim.x + threadIdx.x;
  if (z < 4) {
    const float* src = z == 0 ? Wq : z == 1 ? Wk : z == 2 ? Wv : Wo;
    u16* dst = z < 3 ? wqkvT + z * 512 * 512 : woT;
    const float scale = (z == 0) ? CEXP : 1.0f;
    for (int i = i0; i < 512 * 512; i += stride) {
      int n = i >> 9, k = i & 511;
      dst[i] = f2bf(src[k * 512 + n] * scale);   // out[n*512+k] = in[k,n]
    }
  } else {
    const float* src = z == 4 ? w1 : w2;
    u16* dst = z == 4 ? w1b : w2b;
    for (int i = i0; i < 2048 * 512; i += stride) dst[i] = f2bf(src[i]);
  }
}

// ---------- LayerNorm row kernel (+ optional bf16 cast of K,V rows) ----------
template <bool KV>
__launch_bounds__(128)
__global__ void ln_cast(const float* __restrict__ X, const float* __restrict__ gw,
                        const float* __restrict__ bw, u16* __restrict__ Y,
                        const float* __restrict__ Kin, const float* __restrict__ Vin,
                        u16* __restrict__ Kb, u16* __restrict__ Vb) {
  const int row = blockIdx.x, t = threadIdx.x;
  const size_t base = (size_t)row * 512;
  float4 x = ((const float4*)(X + base))[t];
  float s = x.x + x.y + x.z + x.w;
  float ss = x.x * x.x + x.y * x.y + x.z * x.z + x.w * x.w;
#pragma unroll
  for (int off = 32; off > 0; off >>= 1) {
    s += __shfl_xor(s, off);
    ss += __shfl_xor(ss, off);
  }
  __shared__ float red[4];
  if ((t & 63) == 0) { red[(t >> 6) * 2] = s; red[(t >> 6) * 2 + 1] = ss; }
  __syncthreads();
  const float tot = red[0] + red[2], tss = red[1] + red[3];
  const float mu = tot * (1.0f / 512.0f);
  const float var = tss * (1.0f / 512.0f) - mu * mu;
  const float rs = rsqrtf(var + 1e-5f);
  float4 g4 = ((const float4*)gw)[t];
  float4 b4 = ((const float4*)bw)[t];
  us4 o;
  o.x = f2bf((x.x - mu) * rs * g4.x + b4.x);
  o.y = f2bf((x.y - mu) * rs * g4.y + b4.y);
  o.z = f2bf((x.z - mu) * rs * g4.z + b4.z);
  o.w = f2bf((x.w - mu) * rs * g4.w + b4.w);
  ((us4*)(Y + base))[t] = o;
  if constexpr (KV) {
    float4 k4 = ((const float4*)(Kin + base))[t];
    float4 v4 = ((const float4*)(Vin + base))[t];
    us4 ko, vo;
    ko.x = f2bf(k4.x); ko.y = f2bf(k4.y); ko.z = f2bf(k4.z); ko.w = f2bf(k4.w);
    vo.x = f2bf(v4.x); vo.y = f2bf(v4.y); vo.z = f2bf(v4.z); vo.w = f2bf(v4.w);
    ((us4*)(Kb + base))[t] = ko;
    ((us4*)(Vb + base))[t] = vo;
  }
}

// ---------- merged QKV projection GEMM (XOR-swizzled LDS chunks) ----------
__launch_bounds__(256, 3)
__global__ void gemm_qkv(const u16* __restrict__ Aq, const u16* __restrict__ Ak,
                         const u16* __restrict__ Av, const u16* __restrict__ Bt,
                         u16* __restrict__ qb, u16* __restrict__ kb, u16* __restrict__ vtb) {
  __shared__ __align__(16) u16 sA[128 * 32];
  __shared__ __align__(16) u16 sB[128 * 32];
  const int tid = threadIdx.x;
  const int wave = tid >> 6, lane = tid & 63;
  const int l15 = lane & 15, quad = lane >> 4;
  const int qsw = (quad ^ ((l15 >> 1) & 3)) * 8;
  const int m0 = blockIdx.x * 128, n0 = blockIdx.y * 128;
  const int sel = n0 >> 9;  // 0=q, 1=k, 2=v
  const u16* A = sel == 0 ? Aq : sel == 1 ? Ak : Av;
  const int wm = (wave >> 1) * 64, wn = (wave & 1) * 64;
  const int u0 = wave * 64 + lane, u1 = u0 + 256;
  const int sw0 = ((u0 & 3) ^ ((u0 >> 3) & 3)) * 8;  // same value for u1
  const int K = 512;

  const u16* a0 = A + (size_t)(m0 + (u0 >> 2)) * K + sw0;
  const u16* a1 = A + (size_t)(m0 + (u1 >> 2)) * K + sw0;
  const u16* b0 = Bt + (size_t)(n0 + (u0 >> 2)) * K + sw0;
  const u16* b1p = Bt + (size_t)(n0 + (u1 >> 2)) * K + sw0;

  f32x4 acc[4][4] = {};
  for (int k0 = 0; k0 < K; k0 += 32) {
    async_load16(a0 + k0, &sA[wave * 512]);
    async_load16(a1 + k0, &sA[2048 + wave * 512]);
    async_load16(b0 + k0, &sB[wave * 512]);
    async_load16(b1p + k0, &sB[2048 + wave * 512]);
    __syncthreads();
    short8 af[4], bfr[4];
#pragma unroll
    for (int i = 0; i < 4; i++)
      af[i] = *(const short8*)&sA[(wm + i * 16 + l15) * 32 + qsw];
#pragma unroll
    for (int j = 0; j < 4; j++)
      bfr[j] = *(const short8*)&sB[(wn + j * 16 + l15) * 32 + qsw];
#pragma unroll
    for (int i = 0; i < 4; i++)
#pragma unroll
      for (int j = 0; j < 4; j++)
        acc[i][j] = __builtin_amdgcn_mfma_f32_16x16x32_bf16(af[i], bfr[j], acc[i][j], 0, 0, 0);
    __syncthreads();
  }

#pragma unroll
  for (int i = 0; i < 4; i++) {
#pragma unroll
    for (int j = 0; j < 4; j++) {
      const int ocol = ((n0 + wn) & 511) + j * 16 + l15;
      const int row0 = m0 + wm + i * 16 + quad * 4;
      if (sel < 2) {
        u16* C = sel == 0 ? qb : kb;
#pragma unroll
        for (int r = 0; r < 4; r++) C[(size_t)(row0 + r) * 512 + ocol] = f2bf(acc[i][j][r]);
      } else {
        const int b = row0 >> 12, s0 = row0 & 4095;
        const int hh = ocol >> 6, cc = ocol & 63;
        us4 pk;
        pk.x = f2bf(acc[i][j][0]); pk.y = f2bf(acc[i][j][1]);
        pk.z = f2bf(acc[i][j][2]); pk.w = f2bf(acc[i][j][3]);
        *(us4*)&vtb[((size_t)((b * 8 + hh) * 64 + cc) << 12) + s0] = pk;
      }
    }
  }
}

// ---------- GEMM: C[M,N] = A[M,K] @ Bt[N,K]^T (XOR-swizzled LDS chunks) ----------
// EP: 2 = fp32 store + res add | 3 = +bias, exact GELU, bf16 | 4 = +bias +res, fp32
template <int EP, int TN, int LB>
__launch_bounds__(256, LB)
__global__ void gemm_bt(const u16* __restrict__ A, const u16* __restrict__ Bt,
                        int M, int N, int K, void* __restrict__ Cp,
                        const float* __restrict__ bias, const float* __restrict__ res) {
  constexpr int MI = (TN == 128) ? 4 : 2;
  __shared__ __align__(16) u16 sA[128 * 32];
  __shared__ __align__(16) u16 sB[TN * 32];
  const int tid = threadIdx.x;
  const int wave = tid >> 6, lane = tid & 63;
  const int l15 = lane & 15, quad = lane >> 4;
  const int qsw = (quad ^ ((l15 >> 1) & 3)) * 8;
  const int m0 = blockIdx.x * 128, n0 = blockIdx.y * TN;
  const int wm = (TN == 128) ? (wave >> 1) * 64 : wave * 32;
  const int wn = (TN == 128) ? (wave & 1) * 64 : 0;
  const int u0 = wave * 64 + lane, u1 = u0 + 256;
  const int sw0 = ((u0 & 3) ^ ((u0 >> 3) & 3)) * 8;

  const u16* a0 = A + (size_t)(m0 + (u0 >> 2)) * K + sw0;
  const u16* a1 = A + (size_t)(m0 + (u1 >> 2)) * K + sw0;
  const u16* b0 = Bt + (size_t)(n0 + (u0 >> 2)) * K + sw0;

  f32x4 acc[MI][4] = {};
  for (int k0 = 0; k0 < K; k0 += 32) {
    async_load16(a0 + k0, &sA[wave * 512]);
    async_load16(a1 + k0, &sA[2048 + wave * 512]);
    async_load16(b0 + k0, &sB[wave * 512]);
    if constexpr (TN == 128) {
      const u16* b1p = Bt + (size_t)(n0 + (u1 >> 2)) * K + sw0;
      async_load16(b1p + k0, &sB[2048 + wave * 512]);
    }
    __syncthreads();
    short8 af[MI], bfr[4];
#pragma unroll
    for (int i = 0; i < MI; i++)
      af[i] = *(const short8*)&sA[(wm + i * 16 + l15) * 32 + qsw];
#pragma unroll
    for (int j = 0; j < 4; j++)
      bfr[j] = *(const short8*)&sB[(wn + j * 16 + l15) * 32 + qsw];
#pragma unroll
    for (int i = 0; i < MI; i++)
#pragma unroll
      for (int j = 0; j < 4; j++)
        acc[i][j] = __builtin_amdgcn_mfma_f32_16x16x32_bf16(af[i], bfr[j], acc[i][j], 0, 0, 0);
    __syncthreads();
  }

#pragma unroll
  for (int i = 0; i < MI; i++) {
#pragma unroll
    for (int j = 0; j < 4; j++) {
      const int col = n0 + wn + j * 16 + l15;
      const int row0 = m0 + wm + i * 16 + quad * 4;
      if (EP == 2) {
        float* C = (float*)Cp;
#pragma unroll
        for (int r = 0; r < 4; r++) {
          size_t idx = (size_t)(row0 + r) * N + col;
          C[idx] = acc[i][j][r] + res[idx];
        }
      } else if (EP == 3) {
        u16* C = (u16*)Cp;
        const float bv = bias[col];
#pragma unroll
        for (int r = 0; r < 4; r++) {
          float xx = acc[i][j][r] + bv;
          float gl = 0.5f * xx * (1.0f + erff(xx * 0.70710678118f));
          C[(size_t)(row0 + r) * N + col] = f2bf(gl);
        }
      } else {
        float* C = (float*)Cp;
        const float bv = bias[col];
#pragma unroll
        for (int r = 0; r < 4; r++) {
          size_t idx = (size_t)(row0 + r) * N + col;
          C[idx] = acc[i][j][r] + bv + res[idx];
        }
      }
    }
  }
}

// ---------- flash attention: 32x32x16 MFMA, in-register P via permlane32_swap ----------
// q-tile 128 per block, 4 waves x 32 q-rows. grid (S/128, B*H) = 512 blocks (2/CU).
// K tile [128 key][64 d] and V^T tile [64 dv][128 key] in LDS, XOR-swizzled 16B slots
// (slot ^= row&7), staged via global_load_lds with pre-swizzled global source,
// double-buffered (stage t+1 before compute t, one vmcnt(0)+barrier per tile).
// St = K·Q^T (keys = C rows, q = C cols). P never touches LDS: pack to bf16 with
// v_perm, redistribute across lane halves with v_permlane32_swap -> PV B-fragments.
__launch_bounds__(256, 2)
__global__ void attn_kernel(const u16* __restrict__ qb, const u16* __restrict__ kb,
                            const u16* __restrict__ vtb, u16* __restrict__ ctx) {
  __shared__ __align__(16) u16 sK[2][128 * 64];  // 2 x 16 KB
  __shared__ __align__(16) u16 sV[2][64 * 128];  // 2 x 16 KB
  const int tid = threadIdx.x;
  const int wave = tid >> 6, lane = tid & 63;
  const int l31 = lane & 31, hi = lane >> 5;
  const int bh = blockIdx.y, b = bh >> 3, h = bh & 7;
  const int q0 = blockIdx.x * 128;
  const size_t rb = (size_t)b * 4096;
  const int qrow = q0 + wave * 32 + l31;

  // Q B-fragments: qf[ks] elem e -> Q[qrow][h*64 + ks*16 + hi*8 + e]
  short8 qf[4];
#pragma unroll
  for (int ks = 0; ks < 4; ks++)
    qf[ks] = *(const short8*)&qb[(rb + qrow) * 512 + h * 64 + ks * 16 + hi * 8];

  // stage one 128-key tile: K 1024 16B-units, V 1024 16B-units, 4 each per thread.
  // dest is linear (unit u at byte u*16); source slot pre-swizzled: sl = slot' ^ (row&7)
#define STAGE(bufidx, jj)                                                            \
  {                                                                                  \
    _Pragma("unroll") for (int r = 0; r < 4; r++) {                                  \
      int u = r * 256 + wave * 64 + lane;                                            \
      int row = u >> 3, sl = (u & 7) ^ (row & 7);                                    \
      async_load16(&kb[(rb + (jj) + row) * 512 + h * 64 + sl * 8],                   \
                   &sK[bufidx][(r * 256 + wave * 64) * 8]);                          \
    }                                                                                \
    _Pragma("unroll") for (int r = 0; r < 4; r++) {                                  \
      int u = r * 256 + wave * 64 + lane;                                            \
      int row = u >> 4, sl = (u & 15) ^ (row & 7);                                   \
      async_load16(&vtb[((size_t)(bh * 64 + row)) * 4096 + (jj) + sl * 8],           \
                   &sV[bufidx][(r * 256 + wave * 64) * 8]);                          \
    }                                                                                \
  }

  f32x16 ov[2] = {};
  float l_part = 0.f;

  STAGE(0, 0);
  asm volatile("s_waitcnt vmcnt(0)" ::: "memory");
  __syncthreads();

  for (int t = 0; t < 32; t++) {
    const int cur = t & 1;
    if (t < 31) STAGE(cur ^ 1, (t + 1) * 128);
    const u16* K_ = sK[cur];
    const u16* V_ = sV[cur];
#pragma unroll
    for (int kb32 = 0; kb32 < 4; kb32++) {
      // ---- St = K . Q^T over dk=64 (4 k-steps of 16) ----
      f32x16 st = {};
#pragma unroll
      for (int ks = 0; ks < 4; ks++) {
        const int row = kb32 * 32 + l31;
        const int sl = (ks * 2 + hi) ^ (row & 7);
        short8 kf = *(const short8*)&K_[row * 64 + sl * 8];
        st = __builtin_amdgcn_mfma_f32_32x32x16_bf16(kf, qf[ks], st, 0, 0, 0);
      }
      // ---- exp + denominator partial ----
      float p[16];
#pragma unroll
      for (int i = 0; i < 16; i++) p[i] = __builtin_amdgcn_exp2f(st[i]);
#pragma unroll
      for (int i = 0; i < 16; i += 4)
        l_part += (p[i] + p[i + 1]) + (p[i + 2] + p[i + 3]);
      // ---- pack to bf16 and build PV B-fragments in-register ----
      // lane (q=l31, hi) holds keys (reg&3)+8*(reg>>2)+4*hi of this 32-key block.
      unsigned x0 = pack_bf2_trunc(p[0], p[1]), x1 = pack_bf2_trunc(p[2], p[3]);
      unsigned x2 = pack_bf2_trunc(p[4], p[5]), x3 = pack_bf2_trunc(p[6], p[7]);
      unsigned x4 = pack_bf2_trunc(p[8], p[9]), x5 = pack_bf2_trunc(p[10], p[11]);
      unsigned x6 = pack_bf2_trunc(p[12], p[13]), x7 = pack_bf2_trunc(p[14], p[15]);
      auto r0 = __builtin_amdgcn_permlane32_swap(x0, x2, false, false);
      auto r1 = __builtin_amdgcn_permlane32_swap(x1, x3, false, false);
      auto r2 = __builtin_amdgcn_permlane32_swap(x4, x6, false, false);
      auto r3 = __builtin_amdgcn_permlane32_swap(x5, x7, false, false);
      u32x4 w0 = {r0[0], r1[0], r0[1], r1[1]};  // kstep 0: keys kb32*32 + hi*8 + 0..7
      u32x4 w1 = {r2[0], r3[0], r2[1], r3[1]};  // kstep 1: keys kb32*32 + 16 + hi*8 + 0..7
      short8 pf0 = __builtin_bit_cast(short8, w0);
      short8 pf1 = __builtin_bit_cast(short8, w1);
      // ---- PV: o[dv][q] += V^T . P ----
#pragma unroll
      for (int vb = 0; vb < 2; vb++) {
        const int row = vb * 32 + l31;
        const int sl0 = (kb32 * 4 + hi) ^ (row & 7);
        const int sl1 = (kb32 * 4 + 2 + hi) ^ (row & 7);
        short8 vf0 = *(const short8*)&V_[row * 128 + sl0 * 8];
        short8 vf1 = *(const short8*)&V_[row * 128 + sl1 * 8];
        ov[vb] = __builtin_amdgcn_mfma_f32_32x32x16_bf16(vf0, pf0, ov[vb], 0, 0, 0);
        ov[vb] = __builtin_amdgcn_mfma_f32_32x32x16_bf16(vf1, pf1, ov[vb], 0, 0, 0);
      }
    }
    asm volatile("s_waitcnt vmcnt(0)" ::: "memory");
    __syncthreads();
  }
#undef STAGE

  // each q column lives in 2 lanes (hi halves) with disjoint key sets
  float l = l_part + __shfl_xor(l_part, 32);
  const float inv = 1.0f / l;
#pragma unroll
  for (int vb = 0; vb < 2; vb++) {
#pragma unroll
    for (int rg = 0; rg < 4; rg++) {
      us4 o;
      o.x = f2bf(ov[vb][rg * 4 + 0] * inv);
      o.y = f2bf(ov[vb][rg * 4 + 1] * inv);
      o.z = f2bf(ov[vb][rg * 4 + 2] * inv);
      o.w = f2bf(ov[vb][rg * 4 + 3] * inv);
      *(us4*)&ctx[(rb + qrow) * 512 + h * 64 + vb * 32 + rg * 8 + hi * 4] = o;
    }
  }
}

// ---------- launch ----------
extern "C" void kernel_launch(void* const* d_in, const int* in_sizes, int n_in,
                              void* d_out, int out_size, void* d_ws, size_t ws_size,
                              hipStream_t stream) {
  (void)in_sizes; (void)n_in; (void)out_size; (void)ws_size;
  const float* Q = (const float*)d_in[0];
  const float* K = (const float*)d_in[1];
  const float* V = (const float*)d_in[2];
  const float* W_q = (const float*)d_in[3];
  const float* W_k = (const float*)d_in[4];
  const float* W_v = (const float*)d_in[5];
  const float* W_o = (const float*)d_in[6];
  const float* ln1_g = (const float*)d_in[7];
  const float* ln1_b = (const float*)d_in[8];
  const float* ln2_g = (const float*)d_in[9];
  const float* ln2_b = (const float*)d_in[10];
  const float* w1 = (const float*)d_in[11];
  const float* b1 = (const float*)d_in[12];
  const float* w2 = (const float*)d_in[13];
  const float* b2 = (const float*)d_in[14];

  char* w = (char*)d_ws;
  const size_t MB = 1u << 20;
  u16* wqkvT = (u16*)(w);                       // 1.5 MB [1536,512]
  u16* woT = (u16*)(w + 3 * MB / 2);            // 0.5 MB
  u16* w1b = (u16*)(w + 2 * MB);                // 2 MB
  u16* w2b = (u16*)(w + 4 * MB);                // 2 MB
  u16* Qn  = (u16*)(w + 6 * MB);                // 8 MB
  u16* Kb  = (u16*)(w + 14 * MB);               // 8 MB
  u16* Vb  = (u16*)(w + 22 * MB);               // 8 MB
  u16* qb  = (u16*)(w + 30 * MB);               // 8 MB
  u16* kb  = (u16*)(w + 38 * MB);               // 8 MB
  u16* vtb = (u16*)(w + 46 * MB);               // 8 MB
  u16* ctx = (u16*)(w + 54 * MB);               // 8 MB
  float* X = (float*)(w + 62 * MB);             // 16 MB
  u16* Xn  = (u16*)(w + 6 * MB);                // reuse Qn
  u16* hb  = (u16*)(w + 14 * MB);               // reuse Kb/Vb/qb, 32 MB

  prep_weights<<<dim3(128, 6), 256, 0, stream>>>(W_q, W_k, W_v, W_o, w1, w2,
                                                 wqkvT, woT, w1b, w2b);
  ln_cast<true><<<8192, 128, 0, stream>>>(Q, ln1_g, ln1_b, Qn, K, V, Kb, Vb);
  gemm_qkv<<<dim3(64, 12), 256, 0, stream>>>(Qn, Kb, Vb, wqkvT, qb, kb, vtb);
  attn_kernel<<<dim3(32, 16), 256, 0, stream>>>(qb, kb, vtb, ctx);
  gemm_bt<2, 64, 3><<<dim3(64, 8), 256, 0, stream>>>(ctx, woT, 8192, 512, 512, X, nullptr, Q);
  ln_cast<false><<<8192, 128, 0, stream>>>(X, ln2_g, ln2_b, Xn, nullptr, nullptr, nullptr, nullptr);
  gemm_bt<3, 128, 3><<<dim3(64, 16), 256, 0, stream>>>(Xn, w1b, 8192, 2048, 512, hb, b1, nullptr);
  gemm_bt<4, 64, 3><<<dim3(64, 8), 256, 0, stream>>>(hb, w2b, 8192, 512, 2048, (float*)d_out, b2, X);
}

// Round 2
// 335.103 us; speedup vs baseline: 1.0239x; 1.0010x over previous
//
#include <hip/hip_runtime.h>

typedef unsigned short u16;
typedef __attribute__((ext_vector_type(8))) short short8;
typedef __attribute__((ext_vector_type(4))) float f32x4;
typedef __attribute__((ext_vector_type(16))) float f32x16;
typedef __attribute__((ext_vector_type(4))) unsigned u32x4;

struct __align__(8) us4 { u16 x, y, z, w; };
struct __align__(8) ui2 { unsigned x, y; };

// log2(e) / (sqrt(64) + 1e-6)  -- folded into W_q at prep time
#define CEXP (1.44269504089f / (8.0f + 1e-6f))

// ---------- helpers ----------
__device__ __forceinline__ u16 f2bf(float f) {
  unsigned u = __builtin_bit_cast(unsigned, f);
  unsigned r = (u + 0x7FFFu + ((u >> 16) & 1u)) >> 16;  // RNE
  return (u16)r;
}

// truncation pack: {bf16(b)[hi16] , bf16(a)[lo16]} in ONE v_perm_b32
__device__ __forceinline__ unsigned pack_bf2_trunc(float a, float b) {
  return __builtin_amdgcn_perm(__builtin_bit_cast(unsigned, b),
                               __builtin_bit_cast(unsigned, a), 0x07060302u);
}

__device__ __forceinline__ void async_load16(const void* g, void* l) {
  __builtin_amdgcn_global_load_lds((const __attribute__((address_space(1))) void*)g,
                                   (__attribute__((address_space(3))) void*)l, 16, 0, 0);
}

// ---------- weight prep ----------
// wqkvT: [1536,512] bf16 (rows 0-511 = Wq^T*CEXP, 512-1023 = Wk^T, 1024-1535 = Wv^T)
__global__ void prep_weights(const float* __restrict__ Wq, const float* __restrict__ Wk,
                             const float* __restrict__ Wv, const float* __restrict__ Wo,
                             const float* __restrict__ w1, const float* __restrict__ w2,
                             u16* __restrict__ wqkvT, u16* __restrict__ woT,
                             u16* __restrict__ w1b, u16* __restrict__ w2b) {
  const int z = blockIdx.y;
  const int stride = gridDim.x * blockDim.x;
  const int i0 = blockIdx.x * blockDim.x + threadIdx.x;
  if (z < 4) {
    const float* src = z == 0 ? Wq : z == 1 ? Wk : z == 2 ? Wv : Wo;
    u16* dst = z < 3 ? wqkvT + z * 512 * 512 : woT;
    const float scale = (z == 0) ? CEXP : 1.0f;
    for (int i = i0; i < 512 * 512; i += stride) {
      int n = i >> 9, k = i & 511;
      dst[i] = f2bf(src[k * 512 + n] * scale);   // out[n*512+k] = in[k,n]
    }
  } else {
    const float* src = z == 4 ? w1 : w2;
    u16* dst = z == 4 ? w1b : w2b;
    for (int i = i0; i < 2048 * 512; i += stride) dst[i] = f2bf(src[i]);
  }
}

// ---------- LayerNorm row kernel (+ optional bf16 cast of K,V rows) ----------
template <bool KV>
__launch_bounds__(128)
__global__ void ln_cast(const float* __restrict__ X, const float* __restrict__ gw,
                        const float* __restrict__ bw, u16* __restrict__ Y,
                        const float* __restrict__ Kin, const float* __restrict__ Vin,
                        u16* __restrict__ Kb, u16* __restrict__ Vb) {
  const int row = blockIdx.x, t = threadIdx.x;
  const size_t base = (size_t)row * 512;
  float4 x = ((const float4*)(X + base))[t];
  float s = x.x + x.y + x.z + x.w;
  float ss = x.x * x.x + x.y * x.y + x.z * x.z + x.w * x.w;
#pragma unroll
  for (int off = 32; off > 0; off >>= 1) {
    s += __shfl_xor(s, off);
    ss += __shfl_xor(ss, off);
  }
  __shared__ float red[4];
  if ((t & 63) == 0) { red[(t >> 6) * 2] = s; red[(t >> 6) * 2 + 1] = ss; }
  __syncthreads();
  const float tot = red[0] + red[2], tss = red[1] + red[3];
  const float mu = tot * (1.0f / 512.0f);
  const float var = tss * (1.0f / 512.0f) - mu * mu;
  const float rs = rsqrtf(var + 1e-5f);
  float4 g4 = ((const float4*)gw)[t];
  float4 b4 = ((const float4*)bw)[t];
  us4 o;
  o.x = f2bf((x.x - mu) * rs * g4.x + b4.x);
  o.y = f2bf((x.y - mu) * rs * g4.y + b4.y);
  o.z = f2bf((x.z - mu) * rs * g4.z + b4.z);
  o.w = f2bf((x.w - mu) * rs * g4.w + b4.w);
  ((us4*)(Y + base))[t] = o;
  if constexpr (KV) {
    float4 k4 = ((const float4*)(Kin + base))[t];
    float4 v4 = ((const float4*)(Vin + base))[t];
    us4 ko, vo;
    ko.x = f2bf(k4.x); ko.y = f2bf(k4.y); ko.z = f2bf(k4.z); ko.w = f2bf(k4.w);
    vo.x = f2bf(v4.x); vo.y = f2bf(v4.y); vo.z = f2bf(v4.z); vo.w = f2bf(v4.w);
    ((us4*)(Kb + base))[t] = ko;
    ((us4*)(Vb + base))[t] = vo;
  }
}

// ---------- merged QKV projection GEMM (XOR-swizzled LDS chunks) ----------
__launch_bounds__(256, 3)
__global__ void gemm_qkv(const u16* __restrict__ Aq, const u16* __restrict__ Ak,
                         const u16* __restrict__ Av, const u16* __restrict__ Bt,
                         u16* __restrict__ qb, u16* __restrict__ kb, u16* __restrict__ vtb) {
  __shared__ __align__(16) u16 sA[128 * 32];
  __shared__ __align__(16) u16 sB[128 * 32];
  const int tid = threadIdx.x;
  const int wave = tid >> 6, lane = tid & 63;
  const int l15 = lane & 15, quad = lane >> 4;
  const int qsw = (quad ^ ((l15 >> 1) & 3)) * 8;
  const int m0 = blockIdx.x * 128, n0 = blockIdx.y * 128;
  const int sel = n0 >> 9;  // 0=q, 1=k, 2=v
  const u16* A = sel == 0 ? Aq : sel == 1 ? Ak : Av;
  const int wm = (wave >> 1) * 64, wn = (wave & 1) * 64;
  const int u0 = wave * 64 + lane, u1 = u0 + 256;
  const int sw0 = ((u0 & 3) ^ ((u0 >> 3) & 3)) * 8;  // same value for u1
  const int K = 512;

  const u16* a0 = A + (size_t)(m0 + (u0 >> 2)) * K + sw0;
  const u16* a1 = A + (size_t)(m0 + (u1 >> 2)) * K + sw0;
  const u16* b0 = Bt + (size_t)(n0 + (u0 >> 2)) * K + sw0;
  const u16* b1p = Bt + (size_t)(n0 + (u1 >> 2)) * K + sw0;

  f32x4 acc[4][4] = {};
  for (int k0 = 0; k0 < K; k0 += 32) {
    async_load16(a0 + k0, &sA[wave * 512]);
    async_load16(a1 + k0, &sA[2048 + wave * 512]);
    async_load16(b0 + k0, &sB[wave * 512]);
    async_load16(b1p + k0, &sB[2048 + wave * 512]);
    __syncthreads();
    short8 af[4], bfr[4];
#pragma unroll
    for (int i = 0; i < 4; i++)
      af[i] = *(const short8*)&sA[(wm + i * 16 + l15) * 32 + qsw];
#pragma unroll
    for (int j = 0; j < 4; j++)
      bfr[j] = *(const short8*)&sB[(wn + j * 16 + l15) * 32 + qsw];
#pragma unroll
    for (int i = 0; i < 4; i++)
#pragma unroll
      for (int j = 0; j < 4; j++)
        acc[i][j] = __builtin_amdgcn_mfma_f32_16x16x32_bf16(af[i], bfr[j], acc[i][j], 0, 0, 0);
    __syncthreads();
  }

#pragma unroll
  for (int i = 0; i < 4; i++) {
#pragma unroll
    for (int j = 0; j < 4; j++) {
      const int ocol = ((n0 + wn) & 511) + j * 16 + l15;
      const int row0 = m0 + wm + i * 16 + quad * 4;
      if (sel < 2) {
        u16* C = sel == 0 ? qb : kb;
#pragma unroll
        for (int r = 0; r < 4; r++) C[(size_t)(row0 + r) * 512 + ocol] = f2bf(acc[i][j][r]);
      } else {
        const int b = row0 >> 12, s0 = row0 & 4095;
        const int hh = ocol >> 6, cc = ocol & 63;
        us4 pk;
        pk.x = f2bf(acc[i][j][0]); pk.y = f2bf(acc[i][j][1]);
        pk.z = f2bf(acc[i][j][2]); pk.w = f2bf(acc[i][j][3]);
        *(us4*)&vtb[((size_t)((b * 8 + hh) * 64 + cc) << 12) + s0] = pk;
      }
    }
  }
}

// ---------- GEMM: C[M,N] = A[M,K] @ Bt[N,K]^T (XOR-swizzled LDS chunks) ----------
// EP: 2 = fp32 store + res add | 3 = +bias, exact GELU, bf16 | 4 = +bias +res, fp32
template <int EP, int TN, int LB>
__launch_bounds__(256, LB)
__global__ void gemm_bt(const u16* __restrict__ A, const u16* __restrict__ Bt,
                        int M, int N, int K, void* __restrict__ Cp,
                        const float* __restrict__ bias, const float* __restrict__ res) {
  constexpr int MI = (TN == 128) ? 4 : 2;
  __shared__ __align__(16) u16 sA[128 * 32];
  __shared__ __align__(16) u16 sB[TN * 32];
  const int tid = threadIdx.x;
  const int wave = tid >> 6, lane = tid & 63;
  const int l15 = lane & 15, quad = lane >> 4;
  const int qsw = (quad ^ ((l15 >> 1) & 3)) * 8;
  const int m0 = blockIdx.x * 128, n0 = blockIdx.y * TN;
  const int wm = (TN == 128) ? (wave >> 1) * 64 : wave * 32;
  const int wn = (TN == 128) ? (wave & 1) * 64 : 0;
  const int u0 = wave * 64 + lane, u1 = u0 + 256;
  const int sw0 = ((u0 & 3) ^ ((u0 >> 3) & 3)) * 8;

  const u16* a0 = A + (size_t)(m0 + (u0 >> 2)) * K + sw0;
  const u16* a1 = A + (size_t)(m0 + (u1 >> 2)) * K + sw0;
  const u16* b0 = Bt + (size_t)(n0 + (u0 >> 2)) * K + sw0;

  f32x4 acc[MI][4] = {};
  for (int k0 = 0; k0 < K; k0 += 32) {
    async_load16(a0 + k0, &sA[wave * 512]);
    async_load16(a1 + k0, &sA[2048 + wave * 512]);
    async_load16(b0 + k0, &sB[wave * 512]);
    if constexpr (TN == 128) {
      const u16* b1p = Bt + (size_t)(n0 + (u1 >> 2)) * K + sw0;
      async_load16(b1p + k0, &sB[2048 + wave * 512]);
    }
    __syncthreads();
    short8 af[MI], bfr[4];
#pragma unroll
    for (int i = 0; i < MI; i++)
      af[i] = *(const short8*)&sA[(wm + i * 16 + l15) * 32 + qsw];
#pragma unroll
    for (int j = 0; j < 4; j++)
      bfr[j] = *(const short8*)&sB[(wn + j * 16 + l15) * 32 + qsw];
#pragma unroll
    for (int i = 0; i < MI; i++)
#pragma unroll
      for (int j = 0; j < 4; j++)
        acc[i][j] = __builtin_amdgcn_mfma_f32_16x16x32_bf16(af[i], bfr[j], acc[i][j], 0, 0, 0);
    __syncthreads();
  }

#pragma unroll
  for (int i = 0; i < MI; i++) {
#pragma unroll
    for (int j = 0; j < 4; j++) {
      const int col = n0 + wn + j * 16 + l15;
      const int row0 = m0 + wm + i * 16 + quad * 4;
      if (EP == 2) {
        float* C = (float*)Cp;
#pragma unroll
        for (int r = 0; r < 4; r++) {
          size_t idx = (size_t)(row0 + r) * N + col;
          C[idx] = acc[i][j][r] + res[idx];
        }
      } else if (EP == 3) {
        u16* C = (u16*)Cp;
        const float bv = bias[col];
#pragma unroll
        for (int r = 0; r < 4; r++) {
          float xx = acc[i][j][r] + bv;
          float gl = 0.5f * xx * (1.0f + erff(xx * 0.70710678118f));
          C[(size_t)(row0 + r) * N + col] = f2bf(gl);
        }
      } else {
        float* C = (float*)Cp;
        const float bv = bias[col];
#pragma unroll
        for (int r = 0; r < 4; r++) {
          size_t idx = (size_t)(row0 + r) * N + col;
          C[idx] = acc[i][j][r] + bv + res[idx];
        }
      }
    }
  }
}

// ---------- flash attention: 32x32x16 MFMA, in-register P, 2-way key-split ----------
// 8 waves x 512 threads; q-tile 128 (4 q-groups x 32 rows), each q-group served by a
// pair of waves splitting the 128-key tile (wave = qg + kh*4, kh = key half).
// grid (32,16) = 512 blocks = exactly 2 blocks/CU -> 16 waves/CU (4/SIMD), vs 2/SIMD
// before: same per-pipe totals (LDS ~46%, VALU ~45%, MFMA ~31%) but 2x the TLP to
// overlap them. Each wave accumulates partial (ov, l) over its key half for all 32
// tiles; one LDS merge at the end (reusing the staging LDS).
__launch_bounds__(512, 4)
__global__ void attn_kernel(const u16* __restrict__ qb, const u16* __restrict__ kb,
                            const u16* __restrict__ vtb, u16* __restrict__ ctx) {
  __shared__ __align__(16) u16 sK[2][128 * 64];  // 2 x 16 KB
  __shared__ __align__(16) u16 sV[2][64 * 128];  // 2 x 16 KB
  const int tid = threadIdx.x;
  const int wave = tid >> 6, lane = tid & 63;
  const int l31 = lane & 31, hi = lane >> 5;
  const int qg = wave & 3, kh = wave >> 2;
  const int bh = blockIdx.y, b = bh >> 3, h = bh & 7;
  const int q0 = blockIdx.x * 128;
  const size_t rb = (size_t)b * 4096;
  const int qrow = q0 + qg * 32 + l31;

  // Q B-fragments: qf[ks] elem e -> Q[qrow][h*64 + ks*16 + hi*8 + e]
  short8 qf[4];
#pragma unroll
  for (int ks = 0; ks < 4; ks++)
    qf[ks] = *(const short8*)&qb[(rb + qrow) * 512 + h * 64 + ks * 16 + hi * 8];

  // stage one 128-key tile: K 1024 16B-units, V 1024 16B-units, 2 each per thread.
  // dest linear (unit u at byte u*16); source slot pre-swizzled: sl = slot' ^ (row&7)
#define STAGE(bufidx, jj)                                                            \
  {                                                                                  \
    _Pragma("unroll") for (int r = 0; r < 2; r++) {                                  \
      int u = r * 512 + wave * 64 + lane;                                            \
      int row = u >> 3, sl = (u & 7) ^ (row & 7);                                    \
      async_load16(&kb[(rb + (jj) + row) * 512 + h * 64 + sl * 8],                   \
                   &sK[bufidx][(r * 512 + wave * 64) * 8]);                          \
    }                                                                                \
    _Pragma("unroll") for (int r = 0; r < 2; r++) {                                  \
      int u = r * 512 + wave * 64 + lane;                                            \
      int row = u >> 4, sl = (u & 15) ^ (row & 7);                                   \
      async_load16(&vtb[((size_t)(bh * 64 + row)) * 4096 + (jj) + sl * 8],           \
                   &sV[bufidx][(r * 512 + wave * 64) * 8]);                          \
    }                                                                                \
  }

  f32x16 ov[2] = {};
  float l_part = 0.f;

  STAGE(0, 0);
  asm volatile("s_waitcnt vmcnt(0)" ::: "memory");
  __syncthreads();

  for (int t = 0; t < 32; t++) {
    const int cur = t & 1;
    if (t < 31) STAGE(cur ^ 1, (t + 1) * 128);
    const u16* K_ = sK[cur];
    const u16* V_ = sV[cur];
#pragma unroll
    for (int kk2 = 0; kk2 < 2; kk2++) {
      const int kb32 = kh * 2 + kk2;  // this wave's 32-key block within the tile
      // ---- St = K . Q^T over dk=64 (4 k-steps of 16) ----
      f32x16 st = {};
      __builtin_amdgcn_s_setprio(1);
#pragma unroll
      for (int ks = 0; ks < 4; ks++) {
        const int row = kb32 * 32 + l31;
        const int sl = (ks * 2 + hi) ^ (row & 7);
        short8 kf = *(const short8*)&K_[row * 64 + sl * 8];
        st = __builtin_amdgcn_mfma_f32_32x32x16_bf16(kf, qf[ks], st, 0, 0, 0);
      }
      __builtin_amdgcn_s_setprio(0);
      // ---- exp + denominator partial ----
      float p[16];
#pragma unroll
      for (int i = 0; i < 16; i++) p[i] = __builtin_amdgcn_exp2f(st[i]);
#pragma unroll
      for (int i = 0; i < 16; i += 4)
        l_part += (p[i] + p[i + 1]) + (p[i + 2] + p[i + 3]);
      // ---- pack to bf16 and build PV B-fragments in-register ----
      // lane (q=l31, hi) holds keys (reg&3)+8*(reg>>2)+4*hi of this 32-key block.
      unsigned x0 = pack_bf2_trunc(p[0], p[1]), x1 = pack_bf2_trunc(p[2], p[3]);
      unsigned x2 = pack_bf2_trunc(p[4], p[5]), x3 = pack_bf2_trunc(p[6], p[7]);
      unsigned x4 = pack_bf2_trunc(p[8], p[9]), x5 = pack_bf2_trunc(p[10], p[11]);
      unsigned x6 = pack_bf2_trunc(p[12], p[13]), x7 = pack_bf2_trunc(p[14], p[15]);
      auto r0 = __builtin_amdgcn_permlane32_swap(x0, x2, false, false);
      auto r1 = __builtin_amdgcn_permlane32_swap(x1, x3, false, false);
      auto r2 = __builtin_amdgcn_permlane32_swap(x4, x6, false, false);
      auto r3 = __builtin_amdgcn_permlane32_swap(x5, x7, false, false);
      u32x4 w0 = {r0[0], r1[0], r0[1], r1[1]};  // kstep 0: keys kb32*32 + hi*8 + 0..7
      u32x4 w1 = {r2[0], r3[0], r2[1], r3[1]};  // kstep 1: keys kb32*32 + 16 + hi*8 + 0..7
      short8 pf0 = __builtin_bit_cast(short8, w0);
      short8 pf1 = __builtin_bit_cast(short8, w1);
      // ---- PV: o[dv][q] += V^T . P ----
      __builtin_amdgcn_s_setprio(1);
#pragma unroll
      for (int vb = 0; vb < 2; vb++) {
        const int row = vb * 32 + l31;
        const int sl0 = (kb32 * 4 + hi) ^ (row & 7);
        const int sl1 = (kb32 * 4 + 2 + hi) ^ (row & 7);
        short8 vf0 = *(const short8*)&V_[row * 128 + sl0 * 8];
        short8 vf1 = *(const short8*)&V_[row * 128 + sl1 * 8];
        ov[vb] = __builtin_amdgcn_mfma_f32_32x32x16_bf16(vf0, pf0, ov[vb], 0, 0, 0);
        ov[vb] = __builtin_amdgcn_mfma_f32_32x32x16_bf16(vf1, pf1, ov[vb], 0, 0, 0);
      }
      __builtin_amdgcn_s_setprio(0);
    }
    asm volatile("s_waitcnt vmcnt(0)" ::: "memory");
    __syncthreads();
  }
#undef STAGE

  // ---- key-split merge: wave (qg, kh=1) adds into wave (qg, kh=0) via LDS ----
  // each q column lives in 2 lanes (hi halves) with disjoint key subsets
  float l2 = l_part + __shfl_xor(l_part, 32);
  float* mrg = (float*)&sK[0][0];          // 4 qg x 32 regs x 64 lanes = 32 KB
  float* mrgl = (float*)&sV[0][0];         // 4 qg x 64 lanes
  if (kh == 1) {
#pragma unroll
    for (int vb = 0; vb < 2; vb++)
#pragma unroll
      for (int e = 0; e < 16; e++)
        mrg[(qg * 32 + vb * 16 + e) * 64 + lane] = ov[vb][e];
    mrgl[qg * 64 + lane] = l2;
  }
  __syncthreads();
  if (kh == 0) {
    const float inv = 1.0f / (l2 + mrgl[qg * 64 + lane]);
#pragma unroll
    for (int vb = 0; vb < 2; vb++) {
#pragma unroll
      for (int rg = 0; rg < 4; rg++) {
        us4 o;
        o.x = f2bf((ov[vb][rg * 4 + 0] + mrg[(qg * 32 + vb * 16 + rg * 4 + 0) * 64 + lane]) * inv);
        o.y = f2bf((ov[vb][rg * 4 + 1] + mrg[(qg * 32 + vb * 16 + rg * 4 + 1) * 64 + lane]) * inv);
        o.z = f2bf((ov[vb][rg * 4 + 2] + mrg[(qg * 32 + vb * 16 + rg * 4 + 2) * 64 + lane]) * inv);
        o.w = f2bf((ov[vb][rg * 4 + 3] + mrg[(qg * 32 + vb * 16 + rg * 4 + 3) * 64 + lane]) * inv);
        *(us4*)&ctx[(rb + qrow) * 512 + h * 64 + vb * 32 + rg * 8 + hi * 4] = o;
      }
    }
  }
}

// ---------- launch ----------
extern "C" void kernel_launch(void* const* d_in, const int* in_sizes, int n_in,
                              void* d_out, int out_size, void* d_ws, size_t ws_size,
                              hipStream_t stream) {
  (void)in_sizes; (void)n_in; (void)out_size; (void)ws_size;
  const float* Q = (const float*)d_in[0];
  const float* K = (const float*)d_in[1];
  const float* V = (const float*)d_in[2];
  const float* W_q = (const float*)d_in[3];
  const float* W_k = (const float*)d_in[4];
  const float* W_v = (const float*)d_in[5];
  const float* W_o = (const float*)d_in[6];
  const float* ln1_g = (const float*)d_in[7];
  const float* ln1_b = (const float*)d_in[8];
  const float* ln2_g = (const float*)d_in[9];
  const float* ln2_b = (const float*)d_in[10];
  const float* w1 = (const float*)d_in[11];
  const float* b1 = (const float*)d_in[12];
  const float* w2 = (const float*)d_in[13];
  const float* b2 = (const float*)d_in[14];

  char* w = (char*)d_ws;
  const size_t MB = 1u << 20;
  u16* wqkvT = (u16*)(w);                       // 1.5 MB [1536,512]
  u16* woT = (u16*)(w + 3 * MB / 2);            // 0.5 MB
  u16* w1b = (u16*)(w + 2 * MB);                // 2 MB
  u16* w2b = (u16*)(w + 4 * MB);                // 2 MB
  u16* Qn  = (u16*)(w + 6 * MB);                // 8 MB
  u16* Kb  = (u16*)(w + 14 * MB);               // 8 MB
  u16* Vb  = (u16*)(w + 22 * MB);               // 8 MB
  u16* qb  = (u16*)(w + 30 * MB);               // 8 MB
  u16* kb  = (u16*)(w + 38 * MB);               // 8 MB
  u16* vtb = (u16*)(w + 46 * MB);               // 8 MB
  u16* ctx = (u16*)(w + 54 * MB);               // 8 MB
  float* X = (float*)(w + 62 * MB);             // 16 MB
  u16* Xn  = (u16*)(w + 6 * MB);                // reuse Qn
  u16* hb  = (u16*)(w + 14 * MB);               // reuse Kb/Vb/qb, 32 MB

  prep_weights<<<dim3(128, 6), 256, 0, stream>>>(W_q, W_k, W_v, W_o, w1, w2,
                                                 wqkvT, woT, w1b, w2b);
  ln_cast<true><<<8192, 128, 0, stream>>>(Q, ln1_g, ln1_b, Qn, K, V, Kb, Vb);
  gemm_qkv<<<dim3(64, 12), 256, 0, stream>>>(Qn, Kb, Vb, wqkvT, qb, kb, vtb);
  attn_kernel<<<dim3(32, 16), 512, 0, stream>>>(qb, kb, vtb, ctx);
  gemm_bt<2, 64, 3><<<dim3(64, 8), 256, 0, stream>>>(ctx, woT, 8192, 512, 512, X, nullptr, Q);
  ln_cast<false><<<8192, 128, 0, stream>>>(X, ln2_g, ln2_b, Xn, nullptr, nullptr, nullptr, nullptr);
  gemm_bt<3, 128, 3><<<dim3(64, 16), 256, 0, stream>>>(Xn, w1b, 8192, 2048, 512, hb, b1, nullptr);
  gemm_bt<4, 64, 3><<<dim3(64, 8), 256, 0, stream>>>(hb, w2b, 8192, 512, 2048, (float*)d_out, b2, X);
}

// Round 3
// 322.836 us; speedup vs baseline: 1.0628x; 1.0380x over previous
//
#include <hip/hip_runtime.h>

typedef unsigned short u16;
typedef __attribute__((ext_vector_type(8))) short short8;
typedef __attribute__((ext_vector_type(4))) float f32x4;
typedef __attribute__((ext_vector_type(16))) float f32x16;
typedef __attribute__((ext_vector_type(4))) unsigned u32x4;

struct __align__(8) us4 { u16 x, y, z, w; };
struct __align__(8) ui2 { unsigned x, y; };

// log2(e) / (sqrt(64) + 1e-6)  -- folded into W_q at prep time
#define CEXP (1.44269504089f / (8.0f + 1e-6f))

// ---------- helpers ----------
__device__ __forceinline__ u16 f2bf(float f) {
  unsigned u = __builtin_bit_cast(unsigned, f);
  unsigned r = (u + 0x7FFFu + ((u >> 16) & 1u)) >> 16;  // RNE
  return (u16)r;
}

// truncation pack: {bf16(b)[hi16] , bf16(a)[lo16]} in ONE v_perm_b32
__device__ __forceinline__ unsigned pack_bf2_trunc(float a, float b) {
  return __builtin_amdgcn_perm(__builtin_bit_cast(unsigned, b),
                               __builtin_bit_cast(unsigned, a), 0x07060302u);
}

__device__ __forceinline__ void async_load16(const void* g, void* l) {
  __builtin_amdgcn_global_load_lds((const __attribute__((address_space(1))) void*)g,
                                   (__attribute__((address_space(3))) void*)l, 16, 0, 0);
}

// ---------- weight prep ----------
// wqkvT: [1536,512] bf16 (rows 0-511 = Wq^T*CEXP, 512-1023 = Wk^T, 1024-1535 = Wv^T)
__global__ void prep_weights(const float* __restrict__ Wq, const float* __restrict__ Wk,
                             const float* __restrict__ Wv, const float* __restrict__ Wo,
                             const float* __restrict__ w1, const float* __restrict__ w2,
                             u16* __restrict__ wqkvT, u16* __restrict__ woT,
                             u16* __restrict__ w1b, u16* __restrict__ w2b) {
  const int z = blockIdx.y;
  const int stride = gridDim.x * blockDim.x;
  const int i0 = blockIdx.x * blockDim.x + threadIdx.x;
  if (z < 4) {
    const float* src = z == 0 ? Wq : z == 1 ? Wk : z == 2 ? Wv : Wo;
    u16* dst = z < 3 ? wqkvT + z * 512 * 512 : woT;
    const float scale = (z == 0) ? CEXP : 1.0f;
    for (int i = i0; i < 512 * 512; i += stride) {
      int n = i >> 9, k = i & 511;
      dst[i] = f2bf(src[k * 512 + n] * scale);   // out[n*512+k] = in[k,n]
    }
  } else {
    const float* src = z == 4 ? w1 : w2;
    u16* dst = z == 4 ? w1b : w2b;
    for (int i = i0; i < 2048 * 512; i += stride) dst[i] = f2bf(src[i]);
  }
}

// ---------- LayerNorm row kernel (+ optional bf16 cast of K,V rows) ----------
template <bool KV>
__launch_bounds__(128)
__global__ void ln_cast(const float* __restrict__ X, const float* __restrict__ gw,
                        const float* __restrict__ bw, u16* __restrict__ Y,
                        const float* __restrict__ Kin, const float* __restrict__ Vin,
                        u16* __restrict__ Kb, u16* __restrict__ Vb) {
  const int row = blockIdx.x, t = threadIdx.x;
  const size_t base = (size_t)row * 512;
  float4 x = ((const float4*)(X + base))[t];
  float s = x.x + x.y + x.z + x.w;
  float ss = x.x * x.x + x.y * x.y + x.z * x.z + x.w * x.w;
#pragma unroll
  for (int off = 32; off > 0; off >>= 1) {
    s += __shfl_xor(s, off);
    ss += __shfl_xor(ss, off);
  }
  __shared__ float red[4];
  if ((t & 63) == 0) { red[(t >> 6) * 2] = s; red[(t >> 6) * 2 + 1] = ss; }
  __syncthreads();
  const float tot = red[0] + red[2], tss = red[1] + red[3];
  const float mu = tot * (1.0f / 512.0f);
  const float var = tss * (1.0f / 512.0f) - mu * mu;
  const float rs = rsqrtf(var + 1e-5f);
  float4 g4 = ((const float4*)gw)[t];
  float4 b4 = ((const float4*)bw)[t];
  us4 o;
  o.x = f2bf((x.x - mu) * rs * g4.x + b4.x);
  o.y = f2bf((x.y - mu) * rs * g4.y + b4.y);
  o.z = f2bf((x.z - mu) * rs * g4.z + b4.z);
  o.w = f2bf((x.w - mu) * rs * g4.w + b4.w);
  ((us4*)(Y + base))[t] = o;
  if constexpr (KV) {
    float4 k4 = ((const float4*)(Kin + base))[t];
    float4 v4 = ((const float4*)(Vin + base))[t];
    us4 ko, vo;
    ko.x = f2bf(k4.x); ko.y = f2bf(k4.y); ko.z = f2bf(k4.z); ko.w = f2bf(k4.w);
    vo.x = f2bf(v4.x); vo.y = f2bf(v4.y); vo.z = f2bf(v4.z); vo.w = f2bf(v4.w);
    ((us4*)(Kb + base))[t] = ko;
    ((us4*)(Vb + base))[t] = vo;
  }
}

// ---------- merged QKV projection GEMM (XOR-swizzled LDS chunks) ----------
__launch_bounds__(256, 3)
__global__ void gemm_qkv(const u16* __restrict__ Aq, const u16* __restrict__ Ak,
                         const u16* __restrict__ Av, const u16* __restrict__ Bt,
                         u16* __restrict__ qb, u16* __restrict__ kb, u16* __restrict__ vtb) {
  __shared__ __align__(16) u16 sA[128 * 32];
  __shared__ __align__(16) u16 sB[128 * 32];
  const int tid = threadIdx.x;
  const int wave = tid >> 6, lane = tid & 63;
  const int l15 = lane & 15, quad = lane >> 4;
  const int qsw = (quad ^ ((l15 >> 1) & 3)) * 8;
  const int m0 = blockIdx.x * 128, n0 = blockIdx.y * 128;
  const int sel = n0 >> 9;  // 0=q, 1=k, 2=v
  const u16* A = sel == 0 ? Aq : sel == 1 ? Ak : Av;
  const int wm = (wave >> 1) * 64, wn = (wave & 1) * 64;
  const int u0 = wave * 64 + lane, u1 = u0 + 256;
  const int sw0 = ((u0 & 3) ^ ((u0 >> 3) & 3)) * 8;  // same value for u1
  const int K = 512;

  const u16* a0 = A + (size_t)(m0 + (u0 >> 2)) * K + sw0;
  const u16* a1 = A + (size_t)(m0 + (u1 >> 2)) * K + sw0;
  const u16* b0 = Bt + (size_t)(n0 + (u0 >> 2)) * K + sw0;
  const u16* b1p = Bt + (size_t)(n0 + (u1 >> 2)) * K + sw0;

  f32x4 acc[4][4] = {};
  for (int k0 = 0; k0 < K; k0 += 32) {
    async_load16(a0 + k0, &sA[wave * 512]);
    async_load16(a1 + k0, &sA[2048 + wave * 512]);
    async_load16(b0 + k0, &sB[wave * 512]);
    async_load16(b1p + k0, &sB[2048 + wave * 512]);
    __syncthreads();
    short8 af[4], bfr[4];
#pragma unroll
    for (int i = 0; i < 4; i++)
      af[i] = *(const short8*)&sA[(wm + i * 16 + l15) * 32 + qsw];
#pragma unroll
    for (int j = 0; j < 4; j++)
      bfr[j] = *(const short8*)&sB[(wn + j * 16 + l15) * 32 + qsw];
#pragma unroll
    for (int i = 0; i < 4; i++)
#pragma unroll
      for (int j = 0; j < 4; j++)
        acc[i][j] = __builtin_amdgcn_mfma_f32_16x16x32_bf16(af[i], bfr[j], acc[i][j], 0, 0, 0);
    __syncthreads();
  }

#pragma unroll
  for (int i = 0; i < 4; i++) {
#pragma unroll
    for (int j = 0; j < 4; j++) {
      const int ocol = ((n0 + wn) & 511) + j * 16 + l15;
      const int row0 = m0 + wm + i * 16 + quad * 4;
      if (sel < 2) {
        u16* C = sel == 0 ? qb : kb;
#pragma unroll
        for (int r = 0; r < 4; r++) C[(size_t)(row0 + r) * 512 + ocol] = f2bf(acc[i][j][r]);
      } else {
        const int b = row0 >> 12, s0 = row0 & 4095;
        const int hh = ocol >> 6, cc = ocol & 63;
        us4 pk;
        pk.x = f2bf(acc[i][j][0]); pk.y = f2bf(acc[i][j][1]);
        pk.z = f2bf(acc[i][j][2]); pk.w = f2bf(acc[i][j][3]);
        *(us4*)&vtb[((size_t)((b * 8 + hh) * 64 + cc) << 12) + s0] = pk;
      }
    }
  }
}

// ---------- GEMM: C[M,N] = A[M,K] @ Bt[N,K]^T (XOR-swizzled LDS chunks) ----------
// EP: 2 = fp32 store + res add | 3 = +bias, exact GELU, bf16 | 4 = +bias +res, fp32
template <int EP, int TN, int LB>
__launch_bounds__(256, LB)
__global__ void gemm_bt(const u16* __restrict__ A, const u16* __restrict__ Bt,
                        int M, int N, int K, void* __restrict__ Cp,
                        const float* __restrict__ bias, const float* __restrict__ res) {
  constexpr int MI = (TN == 128) ? 4 : 2;
  __shared__ __align__(16) u16 sA[128 * 32];
  __shared__ __align__(16) u16 sB[TN * 32];
  const int tid = threadIdx.x;
  const int wave = tid >> 6, lane = tid & 63;
  const int l15 = lane & 15, quad = lane >> 4;
  const int qsw = (quad ^ ((l15 >> 1) & 3)) * 8;
  const int m0 = blockIdx.x * 128, n0 = blockIdx.y * TN;
  const int wm = (TN == 128) ? (wave >> 1) * 64 : wave * 32;
  const int wn = (TN == 128) ? (wave & 1) * 64 : 0;
  const int u0 = wave * 64 + lane, u1 = u0 + 256;
  const int sw0 = ((u0 & 3) ^ ((u0 >> 3) & 3)) * 8;

  const u16* a0 = A + (size_t)(m0 + (u0 >> 2)) * K + sw0;
  const u16* a1 = A + (size_t)(m0 + (u1 >> 2)) * K + sw0;
  const u16* b0 = Bt + (size_t)(n0 + (u0 >> 2)) * K + sw0;

  f32x4 acc[MI][4] = {};
  for (int k0 = 0; k0 < K; k0 += 32) {
    async_load16(a0 + k0, &sA[wave * 512]);
    async_load16(a1 + k0, &sA[2048 + wave * 512]);
    async_load16(b0 + k0, &sB[wave * 512]);
    if constexpr (TN == 128) {
      const u16* b1p = Bt + (size_t)(n0 + (u1 >> 2)) * K + sw0;
      async_load16(b1p + k0, &sB[2048 + wave * 512]);
    }
    __syncthreads();
    short8 af[MI], bfr[4];
#pragma unroll
    for (int i = 0; i < MI; i++)
      af[i] = *(const short8*)&sA[(wm + i * 16 + l15) * 32 + qsw];
#pragma unroll
    for (int j = 0; j < 4; j++)
      bfr[j] = *(const short8*)&sB[(wn + j * 16 + l15) * 32 + qsw];
#pragma unroll
    for (int i = 0; i < MI; i++)
#pragma unroll
      for (int j = 0; j < 4; j++)
        acc[i][j] = __builtin_amdgcn_mfma_f32_16x16x32_bf16(af[i], bfr[j], acc[i][j], 0, 0, 0);
    __syncthreads();
  }

#pragma unroll
  for (int i = 0; i < MI; i++) {
#pragma unroll
    for (int j = 0; j < 4; j++) {
      const int col = n0 + wn + j * 16 + l15;
      const int row0 = m0 + wm + i * 16 + quad * 4;
      if (EP == 2) {
        float* C = (float*)Cp;
#pragma unroll
        for (int r = 0; r < 4; r++) {
          size_t idx = (size_t)(row0 + r) * N + col;
          C[idx] = acc[i][j][r] + res[idx];
        }
      } else if (EP == 3) {
        u16* C = (u16*)Cp;
        const float bv = bias[col];
#pragma unroll
        for (int r = 0; r < 4; r++) {
          float xx = acc[i][j][r] + bv;
          float gl = 0.5f * xx * (1.0f + erff(xx * 0.70710678118f));
          C[(size_t)(row0 + r) * N + col] = f2bf(gl);
        }
      } else {
        float* C = (float*)Cp;
        const float bv = bias[col];
#pragma unroll
        for (int r = 0; r < 4; r++) {
          size_t idx = (size_t)(row0 + r) * N + col;
          C[idx] = acc[i][j][r] + bv + res[idx];
        }
      }
    }
  }
}

// ---------- flash attention: 32x32x16 MFMA, in-register P, 2x q-frag reuse ----------
// q-tile 256 per block, 8 waves = 4 q-groups (64 q each) x 2 key-halves.
// grid (16,16) = 256 blocks = exactly 1/CU. Each wave owns TWO 32-q B-fragments, so
// every K-fragment ds_read feeds 2 QK^T MFMAs and every V-fragment ds_read feeds
// 2 PV MFMAs (LDS reads per MFMA halved vs round 2). Triple-buffered K/V staging
// with counted vmcnt(4) (stage t+2 during compute of t; never drain to 0 in-loop).
// Staging addresses advance by pointer increment (no per-tile recompute).
__launch_bounds__(512, 2)
__global__ void attn_kernel(const u16* __restrict__ qb, const u16* __restrict__ kb,
                            const u16* __restrict__ vtb, u16* __restrict__ ctx) {
  // smem: [0 .. 3*8192)      = sK bufs (3 x 16 KB)
  //       [24576 .. 24576+3*8192) = sV bufs (3 x 16 KB)   -> 96 KB total
  __shared__ __align__(16) u16 smem[49152];
  const int tid = threadIdx.x;
  const int wave = tid >> 6, lane = tid & 63;
  const int l31 = lane & 31, hi = lane >> 5;
  const int qg = wave & 3, kh = wave >> 2;
  const int bh = blockIdx.y, b = bh >> 3, h = bh & 7;
  const int q0 = blockIdx.x * 256;
  const size_t rb = (size_t)b * 4096;
  const int qrowA = q0 + qg * 64 + l31;  // frag A q-cols
  const int qrowB = qrowA + 32;          // frag B q-cols

  // Q B-fragments: qf[ks] elem e -> Q[qrow][h*64 + ks*16 + hi*8 + e]
  short8 qfA[4], qfB[4];
#pragma unroll
  for (int ks = 0; ks < 4; ks++) {
    qfA[ks] = *(const short8*)&qb[(rb + qrowA) * 512 + h * 64 + ks * 16 + hi * 8];
    qfB[ks] = *(const short8*)&qb[(rb + qrowB) * 512 + h * 64 + ks * 16 + hi * 8];
  }

  // staging pointers (advance per tile). 512 threads x (2 K + 2 V) 16B units/tile.
  const int uk0 = wave * 64 + lane, uk1 = uk0 + 512;
  const int krow0 = uk0 >> 3, ksl0 = (uk0 & 7) ^ (krow0 & 7);
  const int krow1 = uk1 >> 3, ksl1 = (uk1 & 7) ^ (krow1 & 7);
  const u16* kp0 = kb + (rb + krow0) * 512 + h * 64 + ksl0 * 8;
  const u16* kp1 = kb + (rb + krow1) * 512 + h * 64 + ksl1 * 8;
  const int vrow0 = uk0 >> 4, vsl0 = (uk0 & 15) ^ (vrow0 & 7);
  const int vrow1 = uk1 >> 4, vsl1 = (uk1 & 15) ^ (vrow1 & 7);
  const u16* vp0 = vtb + (size_t)(bh * 64 + vrow0) * 4096 + vsl0 * 8;
  const u16* vp1 = vtb + (size_t)(bh * 64 + vrow1) * 4096 + vsl1 * 8;

#define STAGE(bi)                                                   \
  {                                                                 \
    u16* dK = smem + (bi) * 8192;                                   \
    u16* dV = smem + 24576 + (bi) * 8192;                           \
    async_load16(kp0, &dK[(wave * 64) * 8]);                        \
    async_load16(kp1, &dK[(512 + wave * 64) * 8]);                  \
    async_load16(vp0, &dV[(wave * 64) * 8]);                        \
    async_load16(vp1, &dV[(512 + wave * 64) * 8]);                  \
    kp0 += 128 * 512; kp1 += 128 * 512; vp0 += 128; vp1 += 128;     \
  }

  f32x16 ovA[2] = {}, ovB[2] = {};
  float lA = 0.f, lB = 0.f;

  STAGE(0);
  STAGE(1);
  asm volatile("s_waitcnt vmcnt(4)" ::: "memory");
  __syncthreads();

  for (int t = 0; t < 32; t++) {
    const int cur = t % 3;
    if (t < 30) STAGE((t + 2) % 3);
    const u16* K_ = smem + cur * 8192;
    const u16* V_ = smem + 24576 + cur * 8192;
#pragma unroll
    for (int kk2 = 0; kk2 < 2; kk2++) {
      const int kb32 = kh * 2 + kk2;  // this wave's 32-key block within the tile
      // ---- St = K . Q^T over dk=64; one kf read feeds both q-frags ----
      f32x16 stA = {}, stB = {};
      __builtin_amdgcn_s_setprio(1);
#pragma unroll
      for (int ks = 0; ks < 4; ks++) {
        const int row = kb32 * 32 + l31;
        const int sl = (ks * 2 + hi) ^ (l31 & 7);
        short8 kf = *(const short8*)&K_[row * 64 + sl * 8];
        stA = __builtin_amdgcn_mfma_f32_32x32x16_bf16(kf, qfA[ks], stA, 0, 0, 0);
        stB = __builtin_amdgcn_mfma_f32_32x32x16_bf16(kf, qfB[ks], stB, 0, 0, 0);
      }
      __builtin_amdgcn_s_setprio(0);
      // ---- exp + denominator partials ----
      float pA[16], pB[16];
#pragma unroll
      for (int i = 0; i < 16; i++) pA[i] = __builtin_amdgcn_exp2f(stA[i]);
#pragma unroll
      for (int i = 0; i < 16; i++) pB[i] = __builtin_amdgcn_exp2f(stB[i]);
#pragma unroll
      for (int i = 0; i < 16; i += 4) {
        lA += (pA[i] + pA[i + 1]) + (pA[i + 2] + pA[i + 3]);
        lB += (pB[i] + pB[i + 1]) + (pB[i + 2] + pB[i + 3]);
      }
      // ---- pack to bf16, build PV B-fragments in-register (per frag) ----
      unsigned a0 = pack_bf2_trunc(pA[0], pA[1]), a1 = pack_bf2_trunc(pA[2], pA[3]);
      unsigned a2 = pack_bf2_trunc(pA[4], pA[5]), a3 = pack_bf2_trunc(pA[6], pA[7]);
      unsigned a4 = pack_bf2_trunc(pA[8], pA[9]), a5 = pack_bf2_trunc(pA[10], pA[11]);
      unsigned a6 = pack_bf2_trunc(pA[12], pA[13]), a7 = pack_bf2_trunc(pA[14], pA[15]);
      auto ra0 = __builtin_amdgcn_permlane32_swap(a0, a2, false, false);
      auto ra1 = __builtin_amdgcn_permlane32_swap(a1, a3, false, false);
      auto ra2 = __builtin_amdgcn_permlane32_swap(a4, a6, false, false);
      auto ra3 = __builtin_amdgcn_permlane32_swap(a5, a7, false, false);
      u32x4 wa0 = {ra0[0], ra1[0], ra0[1], ra1[1]};
      u32x4 wa1 = {ra2[0], ra3[0], ra2[1], ra3[1]};
      short8 pfA0 = __builtin_bit_cast(short8, wa0);
      short8 pfA1 = __builtin_bit_cast(short8, wa1);
      unsigned b0 = pack_bf2_trunc(pB[0], pB[1]), b1 = pack_bf2_trunc(pB[2], pB[3]);
      unsigned b2 = pack_bf2_trunc(pB[4], pB[5]), b3 = pack_bf2_trunc(pB[6], pB[7]);
      unsigned b4 = pack_bf2_trunc(pB[8], pB[9]), b5 = pack_bf2_trunc(pB[10], pB[11]);
      unsigned b6 = pack_bf2_trunc(pB[12], pB[13]), b7 = pack_bf2_trunc(pB[14], pB[15]);
      auto rb0 = __builtin_amdgcn_permlane32_swap(b0, b2, false, false);
      auto rb1 = __builtin_amdgcn_permlane32_swap(b1, b3, false, false);
      auto rb2 = __builtin_amdgcn_permlane32_swap(b4, b6, false, false);
      auto rb3 = __builtin_amdgcn_permlane32_swap(b5, b7, false, false);
      u32x4 wb0 = {rb0[0], rb1[0], rb0[1], rb1[1]};
      u32x4 wb1 = {rb2[0], rb3[0], rb2[1], rb3[1]};
      short8 pfB0 = __builtin_bit_cast(short8, wb0);
      short8 pfB1 = __builtin_bit_cast(short8, wb1);
      // ---- PV: one vf read feeds both q-frags ----
      __builtin_amdgcn_s_setprio(1);
#pragma unroll
      for (int vb = 0; vb < 2; vb++) {
        const int row = vb * 32 + l31;
        const int sl0 = (kb32 * 4 + hi) ^ (l31 & 7);
        const int sl1 = (kb32 * 4 + 2 + hi) ^ (l31 & 7);
        short8 vf0 = *(const short8*)&V_[row * 128 + sl0 * 8];
        short8 vf1 = *(const short8*)&V_[row * 128 + sl1 * 8];
        ovA[vb] = __builtin_amdgcn_mfma_f32_32x32x16_bf16(vf0, pfA0, ovA[vb], 0, 0, 0);
        ovA[vb] = __builtin_amdgcn_mfma_f32_32x32x16_bf16(vf1, pfA1, ovA[vb], 0, 0, 0);
        ovB[vb] = __builtin_amdgcn_mfma_f32_32x32x16_bf16(vf0, pfB0, ovB[vb], 0, 0, 0);
        ovB[vb] = __builtin_amdgcn_mfma_f32_32x32x16_bf16(vf1, pfB1, ovB[vb], 0, 0, 0);
      }
      __builtin_amdgcn_s_setprio(0);
    }
    if (t < 31) {
      if (t < 30)
        asm volatile("s_waitcnt vmcnt(4)" ::: "memory");
      else
        asm volatile("s_waitcnt vmcnt(0)" ::: "memory");
      __syncthreads();
    }
  }
#undef STAGE

  // ---- key-split merge: kh=1 partials through LDS into kh=0 waves ----
  float l2A = lA + __shfl_xor(lA, 32);
  float l2B = lB + __shfl_xor(lB, 32);
  __syncthreads();  // all compute reads of smem done before reuse
  float* mrg = (float*)&smem[0];       // ((qg*2+f)*32 + vb*16 + e)*64 + lane : 64 KB
  float* mrgl = (float*)&smem[32768];  // (qg*2+f)*64 + lane : 2 KB
  if (kh == 1) {
#pragma unroll
    for (int vb = 0; vb < 2; vb++)
#pragma unroll
      for (int e = 0; e < 16; e++) {
        mrg[((qg * 2 + 0) * 32 + vb * 16 + e) * 64 + lane] = ovA[vb][e];
        mrg[((qg * 2 + 1) * 32 + vb * 16 + e) * 64 + lane] = ovB[vb][e];
      }
    mrgl[(qg * 2 + 0) * 64 + lane] = l2A;
    mrgl[(qg * 2 + 1) * 64 + lane] = l2B;
  }
  __syncthreads();
  if (kh == 0) {
    const float invA = 1.0f / (l2A + mrgl[(qg * 2 + 0) * 64 + lane]);
    const float invB = 1.0f / (l2B + mrgl[(qg * 2 + 1) * 64 + lane]);
#pragma unroll
    for (int vb = 0; vb < 2; vb++) {
#pragma unroll
      for (int rg = 0; rg < 4; rg++) {
        us4 oA, oB;
        oA.x = f2bf((ovA[vb][rg * 4 + 0] + mrg[((qg * 2 + 0) * 32 + vb * 16 + rg * 4 + 0) * 64 + lane]) * invA);
        oA.y = f2bf((ovA[vb][rg * 4 + 1] + mrg[((qg * 2 + 0) * 32 + vb * 16 + rg * 4 + 1) * 64 + lane]) * invA);
        oA.z = f2bf((ovA[vb][rg * 4 + 2] + mrg[((qg * 2 + 0) * 32 + vb * 16 + rg * 4 + 2) * 64 + lane]) * invA);
        oA.w = f2bf((ovA[vb][rg * 4 + 3] + mrg[((qg * 2 + 0) * 32 + vb * 16 + rg * 4 + 3) * 64 + lane]) * invA);
        *(us4*)&ctx[(rb + qrowA) * 512 + h * 64 + vb * 32 + rg * 8 + hi * 4] = oA;
        oB.x = f2bf((ovB[vb][rg * 4 + 0] + mrg[((qg * 2 + 1) * 32 + vb * 16 + rg * 4 + 0) * 64 + lane]) * invB);
        oB.y = f2bf((ovB[vb][rg * 4 + 1] + mrg[((qg * 2 + 1) * 32 + vb * 16 + rg * 4 + 1) * 64 + lane]) * invB);
        oB.z = f2bf((ovB[vb][rg * 4 + 2] + mrg[((qg * 2 + 1) * 32 + vb * 16 + rg * 4 + 2) * 64 + lane]) * invB);
        oB.w = f2bf((ovB[vb][rg * 4 + 3] + mrg[((qg * 2 + 1) * 32 + vb * 16 + rg * 4 + 3) * 64 + lane]) * invB);
        *(us4*)&ctx[(rb + qrowB) * 512 + h * 64 + vb * 32 + rg * 8 + hi * 4] = oB;
      }
    }
  }
}

// ---------- launch ----------
extern "C" void kernel_launch(void* const* d_in, const int* in_sizes, int n_in,
                              void* d_out, int out_size, void* d_ws, size_t ws_size,
                              hipStream_t stream) {
  (void)in_sizes; (void)n_in; (void)out_size; (void)ws_size;
  const float* Q = (const float*)d_in[0];
  const float* K = (const float*)d_in[1];
  const float* V = (const float*)d_in[2];
  const float* W_q = (const float*)d_in[3];
  const float* W_k = (const float*)d_in[4];
  const float* W_v = (const float*)d_in[5];
  const float* W_o = (const float*)d_in[6];
  const float* ln1_g = (const float*)d_in[7];
  const float* ln1_b = (const float*)d_in[8];
  const float* ln2_g = (const float*)d_in[9];
  const float* ln2_b = (const float*)d_in[10];
  const float* w1 = (const float*)d_in[11];
  const float* b1 = (const float*)d_in[12];
  const float* w2 = (const float*)d_in[13];
  const float* b2 = (const float*)d_in[14];

  char* w = (char*)d_ws;
  const size_t MB = 1u << 20;
  u16* wqkvT = (u16*)(w);                       // 1.5 MB [1536,512]
  u16* woT = (u16*)(w + 3 * MB / 2);            // 0.5 MB
  u16* w1b = (u16*)(w + 2 * MB);                // 2 MB
  u16* w2b = (u16*)(w + 4 * MB);                // 2 MB
  u16* Qn  = (u16*)(w + 6 * MB);                // 8 MB
  u16* Kb  = (u16*)(w + 14 * MB);               // 8 MB
  u16* Vb  = (u16*)(w + 22 * MB);               // 8 MB
  u16* qb  = (u16*)(w + 30 * MB);               // 8 MB
  u16* kb  = (u16*)(w + 38 * MB);               // 8 MB
  u16* vtb = (u16*)(w + 46 * MB);               // 8 MB
  u16* ctx = (u16*)(w + 54 * MB);               // 8 MB
  float* X = (float*)(w + 62 * MB);             // 16 MB
  u16* Xn  = (u16*)(w + 6 * MB);                // reuse Qn
  u16* hb  = (u16*)(w + 14 * MB);               // reuse Kb/Vb/qb, 32 MB

  prep_weights<<<dim3(128, 6), 256, 0, stream>>>(W_q, W_k, W_v, W_o, w1, w2,
                                                 wqkvT, woT, w1b, w2b);
  ln_cast<true><<<8192, 128, 0, stream>>>(Q, ln1_g, ln1_b, Qn, K, V, Kb, Vb);
  gemm_qkv<<<dim3(64, 12), 256, 0, stream>>>(Qn, Kb, Vb, wqkvT, qb, kb, vtb);
  attn_kernel<<<dim3(16, 16), 512, 0, stream>>>(qb, kb, vtb, ctx);
  gemm_bt<2, 64, 3><<<dim3(64, 8), 256, 0, stream>>>(ctx, woT, 8192, 512, 512, X, nullptr, Q);
  ln_cast<false><<<8192, 128, 0, stream>>>(X, ln2_g, ln2_b, Xn, nullptr, nullptr, nullptr, nullptr);
  gemm_bt<3, 128, 3><<<dim3(64, 16), 256, 0, stream>>>(Xn, w1b, 8192, 2048, 512, hb, b1, nullptr);
  gemm_bt<4, 64, 3><<<dim3(64, 8), 256, 0, stream>>>(hb, w2b, 8192, 512, 2048, (float*)d_out, b2, X);
}